// Round 13
// baseline (267.102 us; speedup 1.0000x reference)
//
#include <hip/hip_runtime.h>
#include <hip/hip_bf16.h>

// Problem dims (fixed by reference): B=16, D=512, N=2048, h=8, Nh=256.
#define DD  512
#define NN  2048
#define BB  16
#define NHD 256

typedef unsigned short u16;
typedef __attribute__((ext_vector_type(4))) float f32x4;
typedef __attribute__((ext_vector_type(8))) short s16x8;
typedef __attribute__((ext_vector_type(4))) short s16x4;
typedef __attribute__((ext_vector_type(4))) u16   u16x4;

static __device__ __forceinline__ u16 f2bf(float f) {
  __hip_bfloat16 h = __float2bfloat16(f);
  return *reinterpret_cast<u16*>(&h);
}
static __device__ __forceinline__ float bf2f(u16 u) {
  union { unsigned int i; float f; } v; v.i = ((unsigned int)u) << 16; return v.f;
}
static __device__ __forceinline__ f32x4 mfma_bf16(s16x8 a, s16x8 b, f32x4 c) {
  return __builtin_amdgcn_mfma_f32_16x16x32_bf16(a, b, c, 0, 0, 0);
}
static __device__ __forceinline__ void gload_lds16(const u16* g, u16* l) {
  __builtin_amdgcn_global_load_lds(
      (const __attribute__((address_space(1))) unsigned int*)g,
      (__attribute__((address_space(3))) unsigned int*)l, 16, 0, 0);
}
// raw barrier + compile-time pin (rule 18: sched_barrier after asm waitcnt)
static __device__ __forceinline__ void barrier_raw() {
  __builtin_amdgcn_sched_barrier(0);
  __builtin_amdgcn_s_barrier();
  __builtin_amdgcn_sched_barrier(0);
}
#define WAITCNT(s) do { asm volatile("s_waitcnt " s ::: "memory"); \
                        __builtin_amdgcn_sched_barrier(0); } while (0)

// ---------------------------------------------------------------- weights f32 -> bf16
__global__ __launch_bounds__(256) void k_cvt_w(const float* __restrict__ w0,
                                               const float* __restrict__ w1,
                                               const float* __restrict__ w2,
                                               const float* __restrict__ w3,
                                               u16* __restrict__ out) {
  const float* srcs[4] = {w0, w1, w2, w3};
  const float* s = srcs[blockIdx.y];
  u16* o = out + (size_t)blockIdx.y * (DD * DD);
  int idx = blockIdx.x * 256 + threadIdx.x;
  float4 v = *(const float4*)(s + (size_t)idx * 4);
  u16x4 u = {f2bf(v.x), f2bf(v.y), f2bf(v.z), f2bf(v.w)};
  *(u16x4*)(o + (size_t)idx * 4) = u;
}

// ---------------------------------------------------------------- 3x X (B,D,N) f32 -> XT (B,N,D) bf16
// Round-11 form (best measured: ~85us, 71% occ). Pad 65: both LDS phases 2-way (free).
__global__ __launch_bounds__(256) void k_transpose3(const float* __restrict__ x0,
                                                    const float* __restrict__ x1,
                                                    const float* __restrict__ x2,
                                                    u16* __restrict__ o0,
                                                    u16* __restrict__ o1,
                                                    u16* __restrict__ o2) {
  __shared__ float t[64][65];
  const int tid = threadIdx.x;
  const int z = blockIdx.z, which = z >> 4, b = z & 15;
  const float* X = which == 0 ? x0 : (which == 1 ? x1 : x2);
  u16*       XT = which == 0 ? o0 : (which == 1 ? o1 : o2);
  const int n0 = blockIdx.x * 64, d0 = blockIdx.y * 64;
  const float* Xb = X + ((size_t)b * DD + d0) * NN + n0;
#pragma unroll
  for (int i = 0; i < 4; ++i) {
    int r = (tid >> 4) + i * 16;
    int c = (tid & 15) * 4;
    float4 v = *(const float4*)(Xb + (size_t)r * NN + c);
    t[r][c] = v.x; t[r][c + 1] = v.y; t[r][c + 2] = v.z; t[r][c + 3] = v.w;
  }
  __syncthreads();
  u16* Ob = XT + ((size_t)b * NN + n0) * DD + d0;
#pragma unroll
  for (int i = 0; i < 4; ++i) {
    int n = (tid >> 4) + i * 16;
    int d = (tid & 15) * 4;
    u16x4 u = {f2bf(t[d][n]), f2bf(t[d + 1][n]), f2bf(t[d + 2][n]), f2bf(t[d + 3][n])};
    *(u16x4*)(Ob + (size_t)n * DD + d) = u;
  }
}

// ================================================================ shared GEMM building blocks
#define GEMM_STAGE(Ag, lda, Bg, ldb, buf, kt)                                   \
  {                                                                             \
    _Pragma("unroll")                                                           \
    for (int j = 0; j < 4; ++j) {                                               \
      int s = j * 256 + w * 64 + lane;                                          \
      int row = s >> 3, u = s & 7;                                              \
      int col = ((u ^ (row & 7)) * 8);                                          \
      gload_lds16(Ag + (size_t)row * lda + (kt) * 64 + col, &Ab[buf][s * 8]);   \
      gload_lds16(Bg + (size_t)row * ldb + (kt) * 64 + col, &Bb[buf][s * 8]);   \
    }                                                                           \
  }

#define GEMM_COMPUTE(buf)                                                       \
  {                                                                             \
    _Pragma("unroll")                                                           \
    for (int ks = 0; ks < 2; ++ks) {                                            \
      s16x8 av[4], bv[4];                                                       \
      _Pragma("unroll")                                                         \
      for (int m = 0; m < 4; ++m) {                                             \
        int row = wm + m * 16 + r;                                              \
        av[m] = *(const s16x8*)&Ab[buf][row * 64 + (((ks * 4 + g) ^ (row & 7)) * 8)]; \
      }                                                                         \
      _Pragma("unroll")                                                         \
      for (int nf = 0; nf < 4; ++nf) {                                          \
        int row = wn + nf * 16 + r;                                             \
        bv[nf] = *(const s16x8*)&Bb[buf][row * 64 + (((ks * 4 + g) ^ (row & 7)) * 8)]; \
      }                                                                         \
      _Pragma("unroll")                                                         \
      for (int m = 0; m < 4; ++m)                                               \
        _Pragma("unroll")                                                       \
        for (int nf = 0; nf < 4; ++nf)                                          \
          acc[m][nf] = mfma_bf16(av[m], bv[nf], acc[m][nf]);                    \
    }                                                                           \
  }

#define GEMM_PREAMBLE                                                           \
  __shared__ __align__(16) u16 Ab[2][128 * 64];                                 \
  __shared__ __align__(16) u16 Bb[2][128 * 64];                                 \
  const int tid = threadIdx.x;                                                  \
  const int lane = tid & 63, w = tid >> 6;                                      \
  const int wm = (w >> 1) * 64, wn = (w & 1) * 64;                              \
  const int r = lane & 15, g = lane >> 4;                                       \
  f32x4 acc[4][4] = {};

#define GEMM_MAINLOOP(Ag, lda, Bg, ldb, nkt)                                    \
  GEMM_STAGE(Ag, lda, Bg, ldb, 0, 0);                                           \
  __syncthreads();                                                              \
  for (int kt = 0; kt < (nkt) - 1; ++kt) {                                      \
    GEMM_STAGE(Ag, lda, Bg, ldb, (kt & 1) ^ 1, kt + 1);                         \
    GEMM_COMPUTE(kt & 1);                                                       \
    __syncthreads();                                                            \
  }                                                                             \
  GEMM_COMPUTE(((nkt) - 1) & 1);

// ---------------------------------------------------------------- generic NT GEMM (projections)
template <typename OUT_T>
__global__ __launch_bounds__(256) void k_gemm_nt(
    const u16* __restrict__ A, long long a_bs, int lda,
    const u16* __restrict__ B, long long b_bs, int ldb,
    OUT_T* __restrict__ C, long long c_bs, int ldc, int K) {
  GEMM_PREAMBLE
  const int m0 = blockIdx.x * 128, n0 = blockIdx.y * 128;
  const u16* Ag = A + (size_t)blockIdx.z * a_bs + (size_t)m0 * lda;
  const u16* Bg = B + (size_t)blockIdx.z * b_bs + (size_t)n0 * ldb;
  const int nkt = K >> 6;
  GEMM_MAINLOOP(Ag, lda, Bg, ldb, nkt);

  OUT_T* Cg = C + (size_t)blockIdx.z * c_bs;
#pragma unroll
  for (int m = 0; m < 4; ++m)
#pragma unroll
    for (int nf = 0; nf < 4; ++nf)
#pragma unroll
      for (int j = 0; j < 4; ++j) {
        int row = m0 + wm + m * 16 + g * 4 + j;
        int col = n0 + wn + nf * 16 + r;
        float v = acc[m][nf][j];
        if constexpr (sizeof(OUT_T) == 2) Cg[(size_t)row * ldc + col] = f2bf(v);
        else                              Cg[(size_t)row * ldc + col] = v;
      }
}

// ---------------------------------------------------------------- fused attention (v8)
// Merged-phase schedule: per e-tile (32e) ONE QK phase (8 MFMA over 256n) and ONE
// PV phase (8 MFMA), ring-2 K/V (16KB slots, parity et&1), stages issued at a
// single point (post-QK barrier — v5 safety rule), post-PV barrier ELIMINATED
// (own lgkm0 + next top barrier covers W-A-R). 3 barriers/et (was 6); et loop
// fully unrolled so all ring/addr math is compile-time. LDS 70144B -> 2 blk/CU.
// Per-wave ledger: prologue leaves [K0ab V0ab]; top vmcnt(2) -> K(et) landed;
// post-QK issue K(et+1),V(et+1); pre-PV vmcnt(4) -> V(et) landed; tail 0.
__global__ __launch_bounds__(512, 4) void k_attn_fused(
    const u16* __restrict__ Qdn, const u16* __restrict__ Kdn,
    const u16* __restrict__ VT,  const u16* __restrict__ XqT,
    u16* __restrict__ And) {
  __shared__ __align__(16) u16 L[35072];   // 70144B: Kr 2x8192 | Vr 2x8192 | Ps 64x36
  u16* Kr = L;
  u16* Vr = L + 16384;
  u16* Ps = L + 32768;                     // stride 36 u16 per row

  const int tid = threadIdx.x;
  const int lane = tid & 63, w = tid >> 6;
  const int r = lane & 15, g = lane >> 4;
  const int dq = w >> 1, eh = w & 1;       // QK: wave = (16 d-rows) x (16 e-cols)
  const int nq = w >> 1, dh = w & 1;       // PV: wave = (64 npos) x (32 d-cols)
  const int bid = blockIdx.x;
  const int dt = bid >> 7, hb = bid & 127; // 8 d-tiles of one (b,h) share bid%8 (XCD)
  const int h = hb & 7, b = hb >> 3;
  const int d0 = dt * 64, hn0 = h * NHD;

  const u16* Qg = Qdn + ((size_t)b * DD + d0) * NN + hn0;
  const u16* Kg = Kdn + ((size_t)b * DD) * NN + hn0;
  const u16* Vg = VT + ((size_t)b * NN + hn0) * DD;

  auto stage_ket = [&](int et) {           // K[et*32 +32e][256n] -> Kr[et&1] (16KB, 2 ops)
    u16* dst = Kr + (et & 1) * 8192;
    const u16* src = Kg + (size_t)(et * 32) * NN;
#pragma unroll
    for (int j = 0; j < 2; ++j) {
      int s = j * 512 + tid;               // 1024 slots of 16B; 32 chunks/row
      int row = s >> 5, u = s & 31;
      gload_lds16(src + (size_t)row * NN + ((u ^ (row & 7)) * 8), dst + s * 8);
    }
  };
  auto stage_vet = [&](int et) {           // V[256n][et*32 +32e] -> Vr[et&1] (2x8KB, 2 ops)
    u16* dst = Vr + (et & 1) * 8192;
    int rl = tid >> 2, u = tid & 3;        // 512 slots/sub-slice; 4 chunks/row (64B)
#pragma unroll
    for (int j = 0; j < 2; ++j) {
      int gn = (rl >> 5) * 64 + j * 32 + (rl & 31);
      gload_lds16(Vg + (size_t)gn * DD + et * 32 + ((u ^ (rl & 3)) * 8),
                  dst + j * 4096 + tid * 8);
    }
  };

  // ---- prologue: Q[64][256] staged through Kr+Vr (32KB) -> qf regs, then K0,V0
#pragma unroll
  for (int jj = 0; jj < 4; ++jj) {
    int s = jj * 512 + tid;                // 2048 slots; 32 chunks/row
    int row = s >> 5, u = s & 31;
    gload_lds16(Qg + (size_t)row * NN + ((u ^ (row & 7)) * 8), L + s * 8);
  }
  WAITCNT("vmcnt(0)");
  barrier_raw();
  s16x8 qf[8];                             // 32 VGPR: wave's 16 d-rows x 256 n
  {
    const int qrow = dq * 16 + r;
#pragma unroll
    for (int k2 = 0; k2 < 8; ++k2)
      qf[k2] = *(const s16x8*)&L[qrow * 256 + (((k2 * 4 + g) ^ (qrow & 7)) * 8)];
  }
  WAITCNT("lgkmcnt(0)");
  barrier_raw();                           // Q region free
  stage_ket(0); stage_vet(0);              // outstanding: [K0a K0b V0a V0b]

  float psum[4] = {};
  f32x4 acc_o[2][2][2] = {};               // [n-slice j][ms][nf-d]

#pragma unroll
  for (int et = 0; et < 16; ++et) {
    WAITCNT("vmcnt(2)");                   // K(et) landed (V(et) still out)
    barrier_raw();                         // top: K ready block-wide
    f32x4 acc_s = {};
    const u16* kb = Kr + (et & 1) * 8192;
    const int rowe = eh * 16 + r;
    __builtin_amdgcn_s_setprio(1);
#pragma unroll
    for (int kq = 0; kq < 8; ++kq) {
      s16x8 bv = *(const s16x8*)&kb[rowe * 256 + (((kq * 4 + g) ^ (rowe & 7)) * 8)];
      acc_s = mfma_bf16(qf[kq], bv, acc_s);
    }
    __builtin_amdgcn_s_setprio(0);
    WAITCNT("lgkmcnt(0)");                 // K reads drained
    barrier_raw();                         // post-QK: license slot (et+1)&1 writes
    if (et + 1 < 16) { stage_ket(et + 1); stage_vet(et + 1); }
    // ---- exp -> Ps (stride 36: zero write conflicts), rowsum partials in regs
#pragma unroll
    for (int j = 0; j < 4; ++j) {
      int rowd = dq * 16 + g * 4 + j;
      int cole = eh * 16 + r;
      float p = __expf(acc_s[j] * 0.0625f);   // scale 1/sqrt(Nh)=1/16
      psum[j] += p;
      Ps[rowd * 36 + cole] = f2bf(p);
    }
    WAITCNT("lgkmcnt(0)");                 // Ps writes drained
    if (et < 15) WAITCNT("vmcnt(4)");      // V(et) landed (K/V(et+1) in flight)
    else         WAITCNT("vmcnt(0)");
    barrier_raw();                         // pre-PV: Ps + V(et) ready
    // ---- PV: 8 MFMA, k=32 (whole et) per mfma; pb hoisted (same for both j)
    s16x8 pb[2];
#pragma unroll
    for (int nf = 0; nf < 2; ++nf) {
      int rowd = dh * 32 + nf * 16 + r;
      s16x4 plo = *(const s16x4*)&Ps[rowd * 36 + g * 8];      // 8B-aligned halves
      s16x4 phi = *(const s16x4*)&Ps[rowd * 36 + g * 8 + 4];
      pb[nf] = __builtin_shufflevector(plo, phi, 0, 1, 2, 3, 4, 5, 6, 7);
    }
    __builtin_amdgcn_s_setprio(1);
#pragma unroll
    for (int j = 0; j < 2; ++j) {
      const u16* vb = Vr + (et & 1) * 8192 + j * 4096;
#pragma unroll
      for (int ms = 0; ms < 2; ++ms) {
        int rl = nq * 32 + ms * 16 + r;
        s16x8 av = *(const s16x8*)((const char*)vb + rl * 64 + ((g * 16) ^ ((rl & 3) << 4)));
        acc_o[j][ms][0] = mfma_bf16(av, pb[0], acc_o[j][ms][0]);
        acc_o[j][ms][1] = mfma_bf16(av, pb[1], acc_o[j][ms][1]);
      }
    }
    __builtin_amdgcn_s_setprio(0);
    WAITCNT("lgkmcnt(0)");                 // PV reads drained (next top bar covers W-A-R)
  }

  // ---- rowsum reduce (deterministic; overlays dead Kr region)
  barrier_raw();
  float* rs = (float*)L;                   // [8][16] partials, then [64] inv at +128
#pragma unroll
  for (int j = 0; j < 4; ++j) {
    float v = psum[j];
    v += __shfl_xor(v, 1);
    v += __shfl_xor(v, 2);
    v += __shfl_xor(v, 4);
    v += __shfl_xor(v, 8);
    if (r == 0) rs[w * 16 + g * 4 + j] = v;
  }
  __syncthreads();
  if (tid < 64) {
    int dqi = tid >> 4, i = tid & 15;
    rs[128 + tid] = 1.0f / (rs[(dqi * 2) * 16 + i] + rs[(dqi * 2 + 1) * 16 + i]);
  }
  __syncthreads();

  const u16* Xg = XqT + ((size_t)b * NN + hn0) * DD + d0;
  u16* Ag = And + ((size_t)b * NN + hn0) * DD + d0;
#pragma unroll
  for (int j = 0; j < 2; ++j)
#pragma unroll
    for (int ms = 0; ms < 2; ++ms)
#pragma unroll
      for (int nf = 0; nf < 2; ++nf) {
        const int dc = dh * 32 + nf * 16 + r;
        const float inv = rs[128 + dc];
#pragma unroll
        for (int jj = 0; jj < 4; ++jj) {
          const int npos = nq * 64 + j * 32 + ms * 16 + g * 4 + jj;
          float o = acc_o[j][ms][nf][jj] * inv;
          float xq = bf2f(Xg[(size_t)npos * DD + dc]);
          Ag[(size_t)npos * DD + dc] = f2bf(xq - o);
        }
      }
}

// ----------------------------------------------------------------
extern "C" void kernel_launch(void* const* d_in, const int* in_sizes, int n_in,
                              void* d_out, int out_size, void* d_ws, size_t ws_size,
                              hipStream_t stream) {
  const float* Xq = (const float*)d_in[0];
  const float* Xk = (const float*)d_in[1];
  const float* Xv = (const float*)d_in[2];
  const float* Wq = (const float*)d_in[3];
  const float* Wk = (const float*)d_in[4];
  const float* Wv = (const float*)d_in[5];
  const float* Wo = (const float*)d_in[6];
  float* out = (float*)d_out;

  char* ws = (char*)d_ws;
  const size_t MB = 1024 * 1024;
  // ws (130 MB): Wb [0,2) | XqT [2,34) | XvT->And [34,66) | Qdn [66,98) | XkT [98,130)
  // d_out (64+ MB): VTb [0,32) + Kdn [32,64) as scratch, overwritten by final GEMM.
  u16* Wb  = (u16*)ws;
  u16* XqT = (u16*)(ws + 2 * MB);
  u16* XvT = (u16*)(ws + 34 * MB);
  u16* And = XvT;                                 // XvT dead after V-GEMM
  u16* Qdn = (u16*)(ws + 66 * MB);
  u16* XkT = (u16*)(ws + 98 * MB);
  u16* VTb = (u16*)d_out;
  u16* Kdn = (u16*)d_out + (size_t)BB * NN * DD;

  k_cvt_w<<<dim3(256, 4), 256, 0, stream>>>(Wq, Wk, Wv, Wo, Wb);

  // all three transposes (round-11 form), z = which*16 + b
  k_transpose3<<<dim3(NN / 64, DD / 64, BB * 3), 256, 0, stream>>>(
      Xq, Xk, Xv, XqT, XkT, XvT);

  // VT[b][n][o] = sum_i XvT[b][n][i] * Wv[o][i]
  k_gemm_nt<u16><<<dim3(NN / 128, DD / 128, BB), 256, 0, stream>>>(
      XvT, (long long)NN * DD, DD,
      Wb + 2 * DD * DD, 0, DD,
      VTb, (long long)NN * DD, DD, DD);
  // Qdn[b][o][n]
  k_gemm_nt<u16><<<dim3(DD / 128, NN / 128, BB), 256, 0, stream>>>(
      Wb, 0, DD,
      XqT, (long long)NN * DD, DD,
      Qdn, (long long)DD * NN, NN, DD);
  // Kdn[b][o][n]
  k_gemm_nt<u16><<<dim3(DD / 128, NN / 128, BB), 256, 0, stream>>>(
      Wb + 1 * DD * DD, 0, DD,
      XkT, (long long)NN * DD, DD,
      Kdn, (long long)DD * NN, NN, DD);

  // fused scores/softmax/PV/residual -> And (overlays dead XvT)
  k_attn_fused<<<dim3(1024), 512, 0, stream>>>(Qdn, Kdn, VTb, XqT, And);

  // out[b][o][n] = sum_i Wo[o][i] * And[b][n][i]  (fp32; overwrites VTb/Kdn scratch)
  k_gemm_nt<float><<<dim3(DD / 128, NN / 128, BB), 256, 0, stream>>>(
      Wb + 3 * DD * DD, 0, DD,
      And, (long long)NN * DD, DD,
      out, (long long)DD * NN, NN, DD);
}

// Round 14
// 247.014 us; speedup vs baseline: 1.0813x; 1.0813x over previous
//
#include <hip/hip_runtime.h>
#include <hip/hip_bf16.h>

// Problem dims (fixed by reference): B=16, D=512, N=2048, h=8, Nh=256.
#define DD  512
#define NN  2048
#define BB  16
#define NHD 256

typedef unsigned short u16;
typedef __attribute__((ext_vector_type(4))) float f32x4;
typedef __attribute__((ext_vector_type(8))) short s16x8;
typedef __attribute__((ext_vector_type(4))) short s16x4;
typedef __attribute__((ext_vector_type(4))) u16   u16x4;

static __device__ __forceinline__ u16 f2bf(float f) {
  __hip_bfloat16 h = __float2bfloat16(f);
  return *reinterpret_cast<u16*>(&h);
}
static __device__ __forceinline__ float bf2f(u16 u) {
  union { unsigned int i; float f; } v; v.i = ((unsigned int)u) << 16; return v.f;
}
static __device__ __forceinline__ f32x4 mfma_bf16(s16x8 a, s16x8 b, f32x4 c) {
  return __builtin_amdgcn_mfma_f32_16x16x32_bf16(a, b, c, 0, 0, 0);
}
static __device__ __forceinline__ void gload_lds16(const u16* g, u16* l) {
  __builtin_amdgcn_global_load_lds(
      (const __attribute__((address_space(1))) unsigned int*)g,
      (__attribute__((address_space(3))) unsigned int*)l, 16, 0, 0);
}
// raw barrier + compile-time pin (rule 18: sched_barrier after asm waitcnt)
static __device__ __forceinline__ void barrier_raw() {
  __builtin_amdgcn_sched_barrier(0);
  __builtin_amdgcn_s_barrier();
  __builtin_amdgcn_sched_barrier(0);
}
#define WAITCNT(s) do { asm volatile("s_waitcnt " s ::: "memory"); \
                        __builtin_amdgcn_sched_barrier(0); } while (0)

// ---------------------------------------------------------------- weights f32 -> bf16
__global__ __launch_bounds__(256) void k_cvt_w(const float* __restrict__ w0,
                                               const float* __restrict__ w1,
                                               const float* __restrict__ w2,
                                               const float* __restrict__ w3,
                                               u16* __restrict__ out) {
  const float* srcs[4] = {w0, w1, w2, w3};
  const float* s = srcs[blockIdx.y];
  u16* o = out + (size_t)blockIdx.y * (DD * DD);
  int idx = blockIdx.x * 256 + threadIdx.x;
  float4 v = *(const float4*)(s + (size_t)idx * 4);
  u16x4 u = {f2bf(v.x), f2bf(v.y), f2bf(v.z), f2bf(v.w)};
  *(u16x4*)(o + (size_t)idx * 4) = u;
}

// ---------------------------------------------------------------- 3x X (B,D,N) f32 -> XT (B,N,D) bf16
// Round-11 form (best measured: ~85us, 71% occ). Pad 65: both LDS phases 2-way (free).
__global__ __launch_bounds__(256) void k_transpose3(const float* __restrict__ x0,
                                                    const float* __restrict__ x1,
                                                    const float* __restrict__ x2,
                                                    u16* __restrict__ o0,
                                                    u16* __restrict__ o1,
                                                    u16* __restrict__ o2) {
  __shared__ float t[64][65];
  const int tid = threadIdx.x;
  const int z = blockIdx.z, which = z >> 4, b = z & 15;
  const float* X = which == 0 ? x0 : (which == 1 ? x1 : x2);
  u16*       XT = which == 0 ? o0 : (which == 1 ? o1 : o2);
  const int n0 = blockIdx.x * 64, d0 = blockIdx.y * 64;
  const float* Xb = X + ((size_t)b * DD + d0) * NN + n0;
#pragma unroll
  for (int i = 0; i < 4; ++i) {
    int r = (tid >> 4) + i * 16;
    int c = (tid & 15) * 4;
    float4 v = *(const float4*)(Xb + (size_t)r * NN + c);
    t[r][c] = v.x; t[r][c + 1] = v.y; t[r][c + 2] = v.z; t[r][c + 3] = v.w;
  }
  __syncthreads();
  u16* Ob = XT + ((size_t)b * NN + n0) * DD + d0;
#pragma unroll
  for (int i = 0; i < 4; ++i) {
    int n = (tid >> 4) + i * 16;
    int d = (tid & 15) * 4;
    u16x4 u = {f2bf(t[d][n]), f2bf(t[d + 1][n]), f2bf(t[d + 2][n]), f2bf(t[d + 3][n])};
    *(u16x4*)(Ob + (size_t)n * DD + d) = u;
  }
}

// ================================================================ shared GEMM building blocks
#define GEMM_STAGE(Ag, lda, Bg, ldb, buf, kt)                                   \
  {                                                                             \
    _Pragma("unroll")                                                           \
    for (int j = 0; j < 4; ++j) {                                               \
      int s = j * 256 + w * 64 + lane;                                          \
      int row = s >> 3, u = s & 7;                                              \
      int col = ((u ^ (row & 7)) * 8);                                          \
      gload_lds16(Ag + (size_t)row * lda + (kt) * 64 + col, &Ab[buf][s * 8]);   \
      gload_lds16(Bg + (size_t)row * ldb + (kt) * 64 + col, &Bb[buf][s * 8]);   \
    }                                                                           \
  }

#define GEMM_COMPUTE(buf)                                                       \
  {                                                                             \
    _Pragma("unroll")                                                           \
    for (int ks = 0; ks < 2; ++ks) {                                            \
      s16x8 av[4], bv[4];                                                       \
      _Pragma("unroll")                                                         \
      for (int m = 0; m < 4; ++m) {                                             \
        int row = wm + m * 16 + r;                                              \
        av[m] = *(const s16x8*)&Ab[buf][row * 64 + (((ks * 4 + g) ^ (row & 7)) * 8)]; \
      }                                                                         \
      _Pragma("unroll")                                                         \
      for (int nf = 0; nf < 4; ++nf) {                                          \
        int row = wn + nf * 16 + r;                                             \
        bv[nf] = *(const s16x8*)&Bb[buf][row * 64 + (((ks * 4 + g) ^ (row & 7)) * 8)]; \
      }                                                                         \
      _Pragma("unroll")                                                         \
      for (int m = 0; m < 4; ++m)                                               \
        _Pragma("unroll")                                                       \
        for (int nf = 0; nf < 4; ++nf)                                          \
          acc[m][nf] = mfma_bf16(av[m], bv[nf], acc[m][nf]);                    \
    }                                                                           \
  }

#define GEMM_PREAMBLE                                                           \
  __shared__ __align__(16) u16 Ab[2][128 * 64];                                 \
  __shared__ __align__(16) u16 Bb[2][128 * 64];                                 \
  const int tid = threadIdx.x;                                                  \
  const int lane = tid & 63, w = tid >> 6;                                      \
  const int wm = (w >> 1) * 64, wn = (w & 1) * 64;                              \
  const int r = lane & 15, g = lane >> 4;                                       \
  f32x4 acc[4][4] = {};

#define GEMM_MAINLOOP(Ag, lda, Bg, ldb, nkt)                                    \
  GEMM_STAGE(Ag, lda, Bg, ldb, 0, 0);                                           \
  __syncthreads();                                                              \
  for (int kt = 0; kt < (nkt) - 1; ++kt) {                                      \
    GEMM_STAGE(Ag, lda, Bg, ldb, (kt & 1) ^ 1, kt + 1);                         \
    GEMM_COMPUTE(kt & 1);                                                       \
    __syncthreads();                                                            \
  }                                                                             \
  GEMM_COMPUTE(((nkt) - 1) & 1);

// ---------------------------------------------------------------- generic NT GEMM (projections)
template <typename OUT_T>
__global__ __launch_bounds__(256) void k_gemm_nt(
    const u16* __restrict__ A, long long a_bs, int lda,
    const u16* __restrict__ B, long long b_bs, int ldb,
    OUT_T* __restrict__ C, long long c_bs, int ldc, int K) {
  GEMM_PREAMBLE
  const int m0 = blockIdx.x * 128, n0 = blockIdx.y * 128;
  const u16* Ag = A + (size_t)blockIdx.z * a_bs + (size_t)m0 * lda;
  const u16* Bg = B + (size_t)blockIdx.z * b_bs + (size_t)n0 * ldb;
  const int nkt = K >> 6;
  GEMM_MAINLOOP(Ag, lda, Bg, ldb, nkt);

  OUT_T* Cg = C + (size_t)blockIdx.z * c_bs;
#pragma unroll
  for (int m = 0; m < 4; ++m)
#pragma unroll
    for (int nf = 0; nf < 4; ++nf)
#pragma unroll
      for (int j = 0; j < 4; ++j) {
        int row = m0 + wm + m * 16 + g * 4 + j;
        int col = n0 + wn + nf * 16 + r;
        float v = acc[m][nf][j];
        if constexpr (sizeof(OUT_T) == 2) Cg[(size_t)row * ldc + col] = f2bf(v);
        else                              Cg[(size_t)row * ldc + col] = v;
      }
}

// ---------------------------------------------------------------- fused attention (v9)
// = v8 merged-phase schedule (3 barriers/et, ring-2 K/V, single stage point,
// PASSED correctness) with the spill fixed: et loop is ROLLED (v8's full unroll
// made the compiler hoist 16 iterations of staging state -> 68MB scratch
// traffic, WRITE 80MB). Ring parity et&1 is 1 VALU op at runtime.
// Per-wave ledger: prologue leaves [K0ab V0ab]; top vmcnt(2) -> K(et) landed;
// post-QK issue K(et+1),V(et+1); pre-PV vmcnt(4) -> V(et) landed; tail 0.
__global__ __launch_bounds__(512, 4) void k_attn_fused(
    const u16* __restrict__ Qdn, const u16* __restrict__ Kdn,
    const u16* __restrict__ VT,  const u16* __restrict__ XqT,
    u16* __restrict__ And) {
  __shared__ __align__(16) u16 L[35072];   // 70144B: Kr 2x8192 | Vr 2x8192 | Ps 64x36
  u16* Kr = L;
  u16* Vr = L + 16384;
  u16* Ps = L + 32768;                     // stride 36 u16 per row

  const int tid = threadIdx.x;
  const int lane = tid & 63, w = tid >> 6;
  const int r = lane & 15, g = lane >> 4;
  const int dq = w >> 1, eh = w & 1;       // QK: wave = (16 d-rows) x (16 e-cols)
  const int nq = w >> 1, dh = w & 1;       // PV: wave = (64 npos) x (32 d-cols)
  const int bid = blockIdx.x;
  const int dt = bid >> 7, hb = bid & 127; // 8 d-tiles of one (b,h) share bid%8 (XCD)
  const int h = hb & 7, b = hb >> 3;
  const int d0 = dt * 64, hn0 = h * NHD;

  const u16* Qg = Qdn + ((size_t)b * DD + d0) * NN + hn0;
  const u16* Kg = Kdn + ((size_t)b * DD) * NN + hn0;
  const u16* Vg = VT + ((size_t)b * NN + hn0) * DD;

  auto stage_ket = [&](int et) {           // K[et*32 +32e][256n] -> Kr[et&1] (16KB, 2 ops)
    u16* dst = Kr + (et & 1) * 8192;
    const u16* src = Kg + (size_t)(et * 32) * NN;
#pragma unroll
    for (int j = 0; j < 2; ++j) {
      int s = j * 512 + tid;               // 1024 slots of 16B; 32 chunks/row
      int row = s >> 5, u = s & 31;
      gload_lds16(src + (size_t)row * NN + ((u ^ (row & 7)) * 8), dst + s * 8);
    }
  };
  auto stage_vet = [&](int et) {           // V[256n][et*32 +32e] -> Vr[et&1] (2x8KB, 2 ops)
    u16* dst = Vr + (et & 1) * 8192;
    int rl = tid >> 2, u = tid & 3;        // 512 slots/sub-slice; 4 chunks/row (64B)
#pragma unroll
    for (int j = 0; j < 2; ++j) {
      int gn = (rl >> 5) * 64 + j * 32 + (rl & 31);
      gload_lds16(Vg + (size_t)gn * DD + et * 32 + ((u ^ (rl & 3)) * 8),
                  dst + j * 4096 + tid * 8);
    }
  };

  // ---- prologue: Q[64][256] staged through Kr+Vr (32KB) -> qf regs, then K0,V0
#pragma unroll
  for (int jj = 0; jj < 4; ++jj) {
    int s = jj * 512 + tid;                // 2048 slots; 32 chunks/row
    int row = s >> 5, u = s & 31;
    gload_lds16(Qg + (size_t)row * NN + ((u ^ (row & 7)) * 8), L + s * 8);
  }
  WAITCNT("vmcnt(0)");
  barrier_raw();
  s16x8 qf[8];                             // 32 VGPR: wave's 16 d-rows x 256 n
  {
    const int qrow = dq * 16 + r;
#pragma unroll
    for (int k2 = 0; k2 < 8; ++k2)
      qf[k2] = *(const s16x8*)&L[qrow * 256 + (((k2 * 4 + g) ^ (qrow & 7)) * 8)];
  }
  WAITCNT("lgkmcnt(0)");
  barrier_raw();                           // Q region free
  stage_ket(0); stage_vet(0);              // outstanding: [K0a K0b V0a V0b]

  float psum[4] = {};
  f32x4 acc_o[2][2][2] = {};               // [n-slice j][ms][nf-d]

  for (int et = 0; et < 16; ++et) {        // ROLLED: minimal live set, no spill
    WAITCNT("vmcnt(2)");                   // K(et) landed (V(et) still out)
    barrier_raw();                         // top: K ready block-wide
    f32x4 acc_s = {};
    const u16* kb = Kr + (et & 1) * 8192;
    const int rowe = eh * 16 + r;
    __builtin_amdgcn_s_setprio(1);
#pragma unroll
    for (int kq = 0; kq < 8; ++kq) {
      s16x8 bv = *(const s16x8*)&kb[rowe * 256 + (((kq * 4 + g) ^ (rowe & 7)) * 8)];
      acc_s = mfma_bf16(qf[kq], bv, acc_s);
    }
    __builtin_amdgcn_s_setprio(0);
    WAITCNT("lgkmcnt(0)");                 // K reads drained
    barrier_raw();                         // post-QK: license slot (et+1)&1 writes
    if (et + 1 < 16) { stage_ket(et + 1); stage_vet(et + 1); }
    // ---- exp -> Ps (stride 36: zero write conflicts), rowsum partials in regs
#pragma unroll
    for (int j = 0; j < 4; ++j) {
      int rowd = dq * 16 + g * 4 + j;
      int cole = eh * 16 + r;
      float p = __expf(acc_s[j] * 0.0625f);   // scale 1/sqrt(Nh)=1/16
      psum[j] += p;
      Ps[rowd * 36 + cole] = f2bf(p);
    }
    WAITCNT("lgkmcnt(0)");                 // Ps writes drained
    if (et < 15) WAITCNT("vmcnt(4)");      // V(et) landed (K/V(et+1) in flight)
    else         WAITCNT("vmcnt(0)");
    barrier_raw();                         // pre-PV: Ps + V(et) ready
    // ---- PV: 8 MFMA, k=32 (whole et); pb hoisted (same for both j)
    s16x8 pb[2];
#pragma unroll
    for (int nf = 0; nf < 2; ++nf) {
      int rowd = dh * 32 + nf * 16 + r;
      s16x4 plo = *(const s16x4*)&Ps[rowd * 36 + g * 8];      // 8B-aligned halves
      s16x4 phi = *(const s16x4*)&Ps[rowd * 36 + g * 8 + 4];
      pb[nf] = __builtin_shufflevector(plo, phi, 0, 1, 2, 3, 4, 5, 6, 7);
    }
    __builtin_amdgcn_s_setprio(1);
#pragma unroll
    for (int j = 0; j < 2; ++j) {
      const u16* vb = Vr + (et & 1) * 8192 + j * 4096;
#pragma unroll
      for (int ms = 0; ms < 2; ++ms) {
        int rl = nq * 32 + ms * 16 + r;
        s16x8 av = *(const s16x8*)((const char*)vb + rl * 64 + ((g * 16) ^ ((rl & 3) << 4)));
        acc_o[j][ms][0] = mfma_bf16(av, pb[0], acc_o[j][ms][0]);
        acc_o[j][ms][1] = mfma_bf16(av, pb[1], acc_o[j][ms][1]);
      }
    }
    __builtin_amdgcn_s_setprio(0);
    WAITCNT("lgkmcnt(0)");                 // PV reads drained (next top bar covers W-A-R)
  }

  // ---- rowsum reduce (deterministic; overlays dead Kr region)
  barrier_raw();
  float* rs = (float*)L;                   // [8][16] partials, then [64] inv at +128
#pragma unroll
  for (int j = 0; j < 4; ++j) {
    float v = psum[j];
    v += __shfl_xor(v, 1);
    v += __shfl_xor(v, 2);
    v += __shfl_xor(v, 4);
    v += __shfl_xor(v, 8);
    if (r == 0) rs[w * 16 + g * 4 + j] = v;
  }
  __syncthreads();
  if (tid < 64) {
    int dqi = tid >> 4, i = tid & 15;
    rs[128 + tid] = 1.0f / (rs[(dqi * 2) * 16 + i] + rs[(dqi * 2 + 1) * 16 + i]);
  }
  __syncthreads();

  const u16* Xg = XqT + ((size_t)b * NN + hn0) * DD + d0;
  u16* Ag = And + ((size_t)b * NN + hn0) * DD + d0;
#pragma unroll
  for (int j = 0; j < 2; ++j)
#pragma unroll
    for (int ms = 0; ms < 2; ++ms)
#pragma unroll
      for (int nf = 0; nf < 2; ++nf) {
        const int dc = dh * 32 + nf * 16 + r;
        const float inv = rs[128 + dc];
#pragma unroll
        for (int jj = 0; jj < 4; ++jj) {
          const int npos = nq * 64 + j * 32 + ms * 16 + g * 4 + jj;
          float o = acc_o[j][ms][nf][jj] * inv;
          float xq = bf2f(Xg[(size_t)npos * DD + dc]);
          Ag[(size_t)npos * DD + dc] = f2bf(xq - o);
        }
      }
}

// ----------------------------------------------------------------
extern "C" void kernel_launch(void* const* d_in, const int* in_sizes, int n_in,
                              void* d_out, int out_size, void* d_ws, size_t ws_size,
                              hipStream_t stream) {
  const float* Xq = (const float*)d_in[0];
  const float* Xk = (const float*)d_in[1];
  const float* Xv = (const float*)d_in[2];
  const float* Wq = (const float*)d_in[3];
  const float* Wk = (const float*)d_in[4];
  const float* Wv = (const float*)d_in[5];
  const float* Wo = (const float*)d_in[6];
  float* out = (float*)d_out;

  char* ws = (char*)d_ws;
  const size_t MB = 1024 * 1024;
  // ws (130 MB): Wb [0,2) | XqT [2,34) | XvT->And [34,66) | Qdn [66,98) | XkT [98,130)
  // d_out (64+ MB): VTb [0,32) + Kdn [32,64) as scratch, overwritten by final GEMM.
  u16* Wb  = (u16*)ws;
  u16* XqT = (u16*)(ws + 2 * MB);
  u16* XvT = (u16*)(ws + 34 * MB);
  u16* And = XvT;                                 // XvT dead after V-GEMM
  u16* Qdn = (u16*)(ws + 66 * MB);
  u16* XkT = (u16*)(ws + 98 * MB);
  u16* VTb = (u16*)d_out;
  u16* Kdn = (u16*)d_out + (size_t)BB * NN * DD;

  k_cvt_w<<<dim3(256, 4), 256, 0, stream>>>(Wq, Wk, Wv, Wo, Wb);

  // all three transposes (round-11 form), z = which*16 + b
  k_transpose3<<<dim3(NN / 64, DD / 64, BB * 3), 256, 0, stream>>>(
      Xq, Xk, Xv, XqT, XkT, XvT);

  // VT[b][n][o] = sum_i XvT[b][n][i] * Wv[o][i]
  k_gemm_nt<u16><<<dim3(NN / 128, DD / 128, BB), 256, 0, stream>>>(
      XvT, (long long)NN * DD, DD,
      Wb + 2 * DD * DD, 0, DD,
      VTb, (long long)NN * DD, DD, DD);
  // Qdn[b][o][n]
  k_gemm_nt<u16><<<dim3(DD / 128, NN / 128, BB), 256, 0, stream>>>(
      Wb, 0, DD,
      XqT, (long long)NN * DD, DD,
      Qdn, (long long)DD * NN, NN, DD);
  // Kdn[b][o][n]
  k_gemm_nt<u16><<<dim3(DD / 128, NN / 128, BB), 256, 0, stream>>>(
      Wb + 1 * DD * DD, 0, DD,
      XkT, (long long)NN * DD, DD,
      Kdn, (long long)DD * NN, NN, DD);

  // fused scores/softmax/PV/residual -> And (overlays dead XvT)
  k_attn_fused<<<dim3(1024), 512, 0, stream>>>(Qdn, Kdn, VTb, XqT, And);

  // out[b][o][n] = sum_i Wo[o][i] * And[b][n][i]  (fp32; overwrites VTb/Kdn scratch)
  k_gemm_nt<float><<<dim3(DD / 128, NN / 128, BB), 256, 0, stream>>>(
      Wb + 3 * DD * DD, 0, DD,
      And, (long long)NN * DD, DD,
      out, (long long)DD * NN, NN, DD);
}